// Round 6
// baseline (218.264 us; speedup 1.0000x reference)
//
#include <hip/hip_runtime.h>
#include <hip/hip_bf16.h>
#include <stdint.h>
#include <math.h>

// ---------------------------------------------------------------------------
// JointAttention: dual-stream rmsnorm -> QKV proj -> RoPE -> joint attention
// over concat(a, x) (4096 tokens, 16 q-heads, 4 kv-heads tiled h%4) -> out proj.
// All matmuls in bf16 MFMA, fp32 accumulate.
//
// R14 = R13 + pipeline upgrades on BOTH the GEMM mainloop and attn:
//  - R13 post-mortem: attn 79.6us (conflicts 49K -- source-side swizzle
//    verified), but non-attn = 137us vs ~50us ideal. gemm64 mainloop was
//    the m233 worst case: 2 barriers/K-step, no prefetch.
//  - GEMM mainloop: 4 K-slots (48 KB LDS), stage slots k+2,k+3 at interval
//    start, compute k,k+1, ONE barrier per 2 K-steps (16 barriers, was 64).
//  - attn: 2-tile barrier intervals: {stage(t+2,t+3); QK(a); QK(b)||exp(a);
//    PV(a)||exp(b); PV(b); bar}. Barriers 64->32; exp(b) (bare in R13) now
//    hides under PV(a) MFMAs. Slot safety: slot written in interval i was
//    last read in interval i-1 (reads drained at its barrier); stages drain
//    at the issuing interval's own end barrier.
// ---------------------------------------------------------------------------

#define NSEQ 2048
#define NJ   4096
#define DIMM 1024

typedef __attribute__((ext_vector_type(4))) float f32x4;
typedef __attribute__((ext_vector_type(8))) short bf16x8;
typedef __attribute__((ext_vector_type(4))) short bf16x4;

__device__ __forceinline__ unsigned short f2bf(float f) {
  union { float f; uint32_t u; } v; v.f = f;
  return (unsigned short)((v.u + 0x7FFFu + ((v.u >> 16) & 1u)) >> 16);
}

__device__ __forceinline__ uint32_t pack2bf(float a, float b) {
  __hip_bfloat162 h = __float22bfloat162_rn(float2{a, b});
  union { __hip_bfloat162 h; uint32_t u; } c; c.h = h;
  return c.u;
}

#if defined(__has_builtin)
#if __has_builtin(__builtin_amdgcn_exp2f)
#define FAST_EXP2(x) __builtin_amdgcn_exp2f(x)
#endif
#endif
#ifndef FAST_EXP2
#define FAST_EXP2(x) exp2f(x)
#endif

// async global->LDS, 16B per lane; LDS dest = wave-uniform base + lane*16
__device__ __forceinline__ void glds16(const void* g, void* l) {
  __builtin_amdgcn_global_load_lds(
      (const __attribute__((address_space(1))) unsigned int*)g,
      (__attribute__((address_space(3))) unsigned int*)l, 16, 0, 0);
}

// ---------------- fused prep: rope tables + weight cast + rmsnorm ----------
__global__ __launch_bounds__(256) void prep_kernel(
    const float* __restrict__ xa, const float* __restrict__ xx,
    const float* __restrict__ ga, const float* __restrict__ gx,
    const float* __restrict__ wqa, const float* __restrict__ wqx,
    const float* __restrict__ wkva, const float* __restrict__ wkvx,
    const float* __restrict__ woa, const float* __restrict__ wox,
    unsigned short* __restrict__ XN, unsigned short* __restrict__ WQT,
    unsigned short* __restrict__ WKVT, unsigned short* __restrict__ WOT,
    float* __restrict__ cosT, float* __restrict__ sinT) {
  __shared__ float tile[32][33];
  __shared__ float red[4];
  int bid = blockIdx.x, t = threadIdx.x;
  if (bid < 256) {
    int idx = bid * 256 + t;                    // exactly NSEQ*32
    int pos = idx >> 5, i = idx & 31;
    double inv = pow(10000.0, -(double)i / 32.0);
    double ang = (double)(2 * pos) * inv;       // t = pos * (4096/2048)
    cosT[idx] = (float)cos(ang);
    sinT[idx] = (float)sin(ang);
  } else if (bid < 6400) {
    int b = bid - 256;
    int z = b >> 10, yx = b & 1023;
    int n0 = (yx >> 5) * 32, k0 = (yx & 31) * 32;
    int s = z & 1, ty = z >> 1;
    int N = (ty == 1) ? 512 : 1024;
    if (n0 >= N) return;                        // block-uniform
    const float* src = (z == 0) ? wqa : (z == 1) ? wqx : (z == 2) ? wkva
                     : (z == 3) ? wkvx : (z == 4) ? woa : wox;
    unsigned short* dst = (ty == 0) ? WQT + (size_t)s * 1024 * 1024
                        : (ty == 1) ? WKVT + (size_t)s * 512 * 1024
                                    : WOT + (size_t)s * 1024 * 1024;
    int r = t >> 3, c4 = (t & 7) * 4;
    f32x4 v = *(const f32x4*)(src + (size_t)(k0 + r) * N + n0 + c4);
    tile[r][c4 + 0] = v.x; tile[r][c4 + 1] = v.y;
    tile[r][c4 + 2] = v.z; tile[r][c4 + 3] = v.w;
    __syncthreads();
    int nn = t >> 3, kk = (t & 7) * 4;
    bf16x4 o;
    o.x = (short)f2bf(tile[kk + 0][nn]);
    o.y = (short)f2bf(tile[kk + 1][nn]);
    o.z = (short)f2bf(tile[kk + 2][nn]);
    o.w = (short)f2bf(tile[kk + 3][nn]);
    *(bf16x4*)(dst + (size_t)(n0 + nn) * 1024 + k0 + kk) = o;
  } else {
    int b = bid - 6400;
    int s = b >> 11, row = b & 2047;
    const float* src = (s == 0 ? xa : xx) + (size_t)row * DIMM;
    const float* g = (s == 0 ? ga : gx);
    f32x4 v = *(const f32x4*)(src + t * 4);
    float ss = v.x * v.x + v.y * v.y + v.z * v.z + v.w * v.w;
#pragma unroll
    for (int o = 32; o > 0; o >>= 1) ss += __shfl_xor(ss, o, 64);
    if ((t & 63) == 0) red[t >> 6] = ss;
    __syncthreads();
    float tot = red[0] + red[1] + red[2] + red[3];
    float rs = rsqrtf(tot * (1.0f / DIMM) + 1e-6f);
    f32x4 gv = *(const f32x4*)(g + t * 4);
    bf16x4 o;
    o.x = (short)f2bf(v.x * rs * gv.x);
    o.y = (short)f2bf(v.y * rs * gv.y);
    o.z = (short)f2bf(v.z * rs * gv.z);
    o.w = (short)f2bf(v.w * rs * gv.w);
    *(bf16x4*)(XN + ((size_t)s * NSEQ + row) * DIMM + t * 4) = o;
  }
}

// ---- shared 64x128x(K=1024) bf16 NT GEMM mainloop, 4-slot pipelined -------
// Wave = 32m x 64n. A slot 64x32 (2048 sh), B slot 128x32 (4096 sh);
// 4 slots each (48 KB). Stage k+2,k+3 at interval start; compute k,k+1;
// ONE barrier per 2 K-steps. Slot written in interval i was last read in
// interval i-1 (reads drained at its barrier); stages drain at the issuing
// interval's end barrier (implicit vmcnt(0)).
__device__ __forceinline__ void gemm64_mainloop(
    const unsigned short* __restrict__ Ag, const unsigned short* __restrict__ Bg,
    unsigned short* As, unsigned short* Bs, f32x4 acc[2][4]) {
  int t = threadIdx.x;
  int lane = t & 63, wid = t >> 6;
  int wm = (wid >> 1) * 32, wn = (wid & 1) * 64;
  int l15 = lane & 15, quad = lane >> 4;
  int srow = t >> 2, sko = (t & 3) * 8;
  const unsigned short* ga = Ag + (size_t)srow * 1024 + sko;
  const unsigned short* gb = Bg + (size_t)srow * 1024 + sko;
  unsigned short* la = As + t * 8;
  unsigned short* lb = Bs + t * 8;
#pragma unroll
  for (int mi = 0; mi < 2; ++mi)
#pragma unroll
    for (int j = 0; j < 4; ++j) acc[mi][j] = (f32x4){0.f, 0.f, 0.f, 0.f};

#define GQ_STAGE(S, KT) do {                                               \
    int k0_ = (KT) * 32;                                                   \
    glds16(ga + k0_, la + (S) * 2048);                                     \
    glds16(gb + k0_, lb + (S) * 4096);                                     \
    glds16(gb + 64 * 1024 + k0_, lb + (S) * 4096 + 2048);                  \
  } while (0)

#define GQ_COMP(S) do {                                                    \
    bf16x8 af[2], bfr[4];                                                  \
    _Pragma("unroll")                                                      \
    for (int mi = 0; mi < 2; ++mi)                                         \
      af[mi] = *(const bf16x8*)(As + (S) * 2048 + (wm + mi * 16 + l15) * 32 + quad * 8); \
    _Pragma("unroll")                                                      \
    for (int j = 0; j < 4; ++j)                                            \
      bfr[j] = *(const bf16x8*)(Bs + (S) * 4096 + (wn + j * 16 + l15) * 32 + quad * 8); \
    _Pragma("unroll")                                                      \
    for (int mi = 0; mi < 2; ++mi)                                         \
      _Pragma("unroll")                                                    \
      for (int j = 0; j < 4; ++j)                                          \
        acc[mi][j] = __builtin_amdgcn_mfma_f32_16x16x32_bf16(af[mi], bfr[j], acc[mi][j], 0, 0, 0); \
  } while (0)

  GQ_STAGE(0, 0);
  GQ_STAGE(1, 1);
  __syncthreads();
  for (int kq = 0; kq < 32; kq += 4) {
    GQ_STAGE(2, (kq + 2) & 31);
    GQ_STAGE(3, (kq + 3) & 31);
    GQ_COMP(0);
    GQ_COMP(1);
    __syncthreads();
    GQ_STAGE(0, (kq + 4) & 31);   // wrap at end: harmless re-stage
    GQ_STAGE(1, (kq + 5) & 31);
    GQ_COMP(2);
    GQ_COMP(3);
    __syncthreads();
  }
#undef GQ_STAGE
#undef GQ_COMP
}

// ------ QKV GEMM: A=[an;xn] (4096x1024), N=1536 (Q 1024 | K 256 | V 256) ---
__global__ __launch_bounds__(256) void gemm_qkv_kernel(
    const unsigned short* __restrict__ XN, const unsigned short* __restrict__ WQT,
    const unsigned short* __restrict__ WKVT, const float* __restrict__ cosT,
    const float* __restrict__ sinT, unsigned short* __restrict__ QB,
    unsigned short* __restrict__ KB, unsigned short* __restrict__ VT) {
  __shared__ unsigned short As[4 * 2048], Bs[4 * 4096];   // 48 KB
  int n0 = blockIdx.x * 128, m0 = blockIdx.y * 64;
  int s = (m0 >= 2048) ? 1 : 0;
  const unsigned short* Ag = XN + (size_t)m0 * 1024;
  const unsigned short* Bg = (n0 < 1024)
      ? WQT + (size_t)s * 1024 * 1024 + (size_t)n0 * 1024
      : WKVT + (size_t)s * 512 * 1024 + (size_t)(n0 - 1024) * 1024;
  f32x4 acc[2][4];
  gemm64_mainloop(Ag, Bg, As, Bs, acc);
  int t = threadIdx.x, lane = t & 63, wid = t >> 6;
  int wm = (wid >> 1) * 32, wn = (wid & 1) * 64;
  int l15 = lane & 15, quad = lane >> 4;
  int coln = n0 + wn;                     // 64-aligned -> head-uniform per wave
  if (coln < 1280) {
    bool isq = coln < 1024;
    float sc = isq ? (1.4426950408889634f / 64.0f) : 1.0f;  // 1/64 * log2(e)
    unsigned short* dstBase;
    if (isq) dstBase = QB + (size_t)(coln >> 6) * NJ * 64;
    else     dstBase = KB + (size_t)((coln - 1024) >> 6) * NJ * 64;
#pragma unroll
    for (int mi = 0; mi < 2; ++mi)
#pragma unroll
      for (int r = 0; r < 4; ++r) {
        int jr = m0 + wm + mi * 16 + quad * 4 + r;   // joint row (a:0..2047, x:2048..)
        int pos = jr & 2047;
#pragma unroll
        for (int jp = 0; jp < 2; ++jp) {             // d = jp*16+l15 pairs with d+32
          int i = jp * 16 + l15;
          float c = cosT[pos * 32 + i], sn = sinT[pos * 32 + i];
          float x1 = acc[mi][jp][r], x2 = acc[mi][jp + 2][r];
          dstBase[(size_t)jr * 64 + jp * 16 + l15]      = f2bf((x1 * c - x2 * sn) * sc);
          dstBase[(size_t)jr * 64 + 32 + jp * 16 + l15] = f2bf((x2 * c + x1 * sn) * sc);
        }
      }
  } else {
    // V: write straight to VT[d][jr] -- acc[mi][j][0..3] are 4 consecutive jr
    int cvb = coln - 1280;
#pragma unroll
    for (int mi = 0; mi < 2; ++mi)
#pragma unroll
      for (int j = 0; j < 4; ++j) {
        int d = cvb + j * 16 + l15;                  // 0..255 = hk*64 + dh
        int jr0 = m0 + wm + mi * 16 + quad * 4;
        union { bf16x4 v; uint32_t u[2]; } pv;
        pv.u[0] = pack2bf(acc[mi][j][0], acc[mi][j][1]);
        pv.u[1] = pack2bf(acc[mi][j][2], acc[mi][j][3]);
        *(bf16x4*)(VT + (size_t)d * NJ + jr0) = pv.v;
      }
  }
}

// ------------- flash attention: 128 q-rows x 1 head per block --------------
// 4 single-tile LDS slots (64x64 bf16, linear, XOR-swizzled content), slot =
// tile&3, staged via glds16 with pre-permuted/pre-swizzled global source
// (K row g(r), chunk c ^= r&7; reads XOR identically -> conflict-free).
// 2-tile barrier intervals: {stage(t+2,t+3); QK(a); QK(b)||exp(a);
// PV(a)||exp(b); PV(b); bar}. 32 barriers total.
__global__ __launch_bounds__(256, 2) void attn_kernel(
    const unsigned short* __restrict__ QB, const unsigned short* __restrict__ KB,
    const unsigned short* __restrict__ VT, unsigned short* __restrict__ AT) {
  __shared__ __align__(16) unsigned short Ks[4][4096];   // 4 slots x 64x64
  __shared__ __align__(16) unsigned short Vs[4][4096];
  int h = blockIdx.y, qt = blockIdx.x;
  int hk = h & 3;                               // jnp.tile -> kv head = h % 4
  int t = threadIdx.x, lane = t & 63, w = t >> 6;
  int l15 = lane & 15, quad = lane >> 4;
  int qsel = w >> 1, ksel = w & 1;
  int q0 = qt * 128 + qsel * 64;                // wave's q rows: q0 + mi*16 + l15
  bf16x8 qf[4][2];
#pragma unroll
  for (int mi = 0; mi < 4; ++mi) {
    const unsigned short* qp = QB + ((size_t)h * NJ + q0 + mi * 16 + l15) * 64;
    qf[mi][0] = *(const bf16x8*)(qp + quad * 8);
    qf[mi][1] = *(const bf16x8*)(qp + 32 + quad * 8);
  }
  f32x4 oT[4][4];                               // O^T partial: [mi][db]
  f32x4 oL[4];                                  // ones-row accum (row0 = lsum)
#pragma unroll
  for (int mi = 0; mi < 4; ++mi) {
    oL[mi] = (f32x4){0.f, 0.f, 0.f, 0.f};
#pragma unroll
    for (int db = 0; db < 4; ++db) oT[mi][db] = (f32x4){0.f, 0.f, 0.f, 0.f};
  }
  bf16x8 vone;                                  // ones A-frag (row 0 only)
  {
    short one = (l15 == 0) ? (short)0x3F80 : (short)0;
    vone = (bf16x8){one, one, one, one, one, one, one, one};
  }
  const unsigned short* Kg = KB + (size_t)hk * NJ * 64;   // [key][d]
  const unsigned short* Vg = VT + (size_t)hk * 64 * NJ;   // [d][key]
  // ---- glds16 source addresses (per thread, loop-invariant) ----
  int r1 = t >> 3, cx = t & 7;
  int e1 = r1 & 7;
  int c1 = cx ^ e1;                             // swizzled 16B chunk
  int gk1 = 32 * (r1 >> 5) + 8 * ((r1 >> 2) & 3) + 4 * ((r1 >> 4) & 1) + (r1 & 3);
  int r2 = r1 + 32;
  int gk2 = 32 * (r2 >> 5) + 8 * ((r2 >> 2) & 3) + 4 * ((r2 >> 4) & 1) + (r2 & 3);
  const unsigned short* sK1 = Kg + (size_t)gk1 * 64 + c1 * 8;   // +tile*4096
  const unsigned short* sK2 = Kg + (size_t)gk2 * 64 + c1 * 8;
  const unsigned short* sV1 = Vg + (size_t)r1 * NJ + c1 * 8;    // +tile*64
  const unsigned short* sV2 = Vg + (size_t)r2 * NJ + c1 * 8;
  // ---- ds_read addresses (per lane, loop-invariant; + slot*4096 shorts) ----
  int e = l15 & 7;
  int co0 = (quad ^ e) * 8;                     // K lo chunk (d 0..31 quarter)
  int co1 = ((4 + quad) ^ e) * 8;               // K hi chunk
  int cov = (((ksel << 2) | quad) ^ e) * 8;     // V chunk (key half ksel)
  const unsigned short* kf0p = &Ks[0][(2 * ksel * 16 + l15) * 64] + co0;
  const unsigned short* kf0q = &Ks[0][(2 * ksel * 16 + l15) * 64] + co1;
  const unsigned short* kf1p = kf0p + 16 * 64;
  const unsigned short* kf1q = kf0q + 16 * 64;
  const unsigned short* vap0 = &Vs[0][(0 * 16 + l15) * 64] + cov;
  const unsigned short* vap1 = &Vs[0][(1 * 16 + l15) * 64] + cov;
  const unsigned short* vap2 = &Vs[0][(2 * 16 + l15) * 64] + cov;
  const unsigned short* vap3 = &Vs[0][(3 * 16 + l15) * 64] + cov;

  f32x4 sxA[4][2], sxB[4][2];
  bf16x8 pbA[4], pbB[4];

#define STAGE(S, T) do {                                                   \
    size_t ko_ = (size_t)(T) * 4096;                                       \
    int vo_ = (T) * 64;                                                    \
    glds16(sK1 + ko_, &Ks[S][0] + t * 8);                                  \
    glds16(sK2 + ko_, &Ks[S][2048] + t * 8);                               \
    glds16(sV1 + vo_, &Vs[S][0] + t * 8);                                  \
    glds16(sV2 + vo_, &Vs[S][2048] + t * 8);                               \
  } while (0)

  // bare QK: tile in slot S -> SX (16 MFMA)
#define QK4(S, SX) do {                                                    \
    bf16x8 k00 = *(const bf16x8*)(kf0p + (S) * 4096);                      \
    bf16x8 k01 = *(const bf16x8*)(kf0q + (S) * 4096);                      \
    bf16x8 k10 = *(const bf16x8*)(kf1p + (S) * 4096);                      \
    bf16x8 k11 = *(const bf16x8*)(kf1q + (S) * 4096);                      \
    _Pragma("unroll")                                                      \
    for (int mi = 0; mi < 4; ++mi) {                                       \
      f32x4 z0 = (f32x4){0.f, 0.f, 0.f, 0.f};                              \
      z0 = __builtin_amdgcn_mfma_f32_16x16x32_bf16(k00, qf[mi][0], z0, 0, 0, 0); \
      z0 = __builtin_amdgcn_mfma_f32_16x16x32_bf16(k01, qf[mi][1], z0, 0, 0, 0); \
      (SX)[mi][0] = z0;                                                    \
      f32x4 z1 = (f32x4){0.f, 0.f, 0.f, 0.f};                              \
      z1 = __builtin_amdgcn_mfma_f32_16x16x32_bf16(k10, qf[mi][0], z1, 0, 0, 0); \
      z1 = __builtin_amdgcn_mfma_f32_16x16x32_bf16(k11, qf[mi][1], z1, 0, 0, 0); \
      (SX)[mi][1] = z1;                                                    \
    }                                                                      \
  } while (0)

  // QK(next, slot SQ) -> SXN interleaved with exp(SXP) -> PB
#define PHASE_A(SQ, SXN, SXP, PB) do {                                     \
    bf16x8 k00 = *(const bf16x8*)(kf0p + (SQ) * 4096);                     \
    bf16x8 k01 = *(const bf16x8*)(kf0q + (SQ) * 4096);                     \
    bf16x8 k10 = *(const bf16x8*)(kf1p + (SQ) * 4096);                     \
    bf16x8 k11 = *(const bf16x8*)(kf1q + (SQ) * 4096);                     \
    _Pragma("unroll")                                                      \
    for (int mi = 0; mi < 4; ++mi) {                                       \
      f32x4 z0 = (f32x4){0.f, 0.f, 0.f, 0.f};                              \
      z0 = __builtin_amdgcn_mfma_f32_16x16x32_bf16(k00, qf[mi][0], z0, 0, 0, 0); \
      z0 = __builtin_amdgcn_mfma_f32_16x16x32_bf16(k01, qf[mi][1], z0, 0, 0, 0); \
      (SXN)[mi][0] = z0;                                                   \
      f32x4 z1 = (f32x4){0.f, 0.f, 0.f, 0.f};                              \
      z1 = __builtin_amdgcn_mfma_f32_16x16x32_bf16(k10, qf[mi][0], z1, 0, 0, 0); \
      z1 = __builtin_amdgcn_mfma_f32_16x16x32_bf16(k11, qf[mi][1], z1, 0, 0, 0); \
      (SXN)[mi][1] = z1;                                                   \
      union { bf16x8 v; uint32_t u[4]; } pk_;                              \
      pk_.u[0] = pack2bf(FAST_EXP2((SXP)[mi][0][0]), FAST_EXP2((SXP)[mi][0][1])); \
      pk_.u[1] = pack2bf(FAST_EXP2((SXP)[mi][0][2]), FAST_EXP2((SXP)[mi][0][3])); \
      pk_.u[2] = pack2bf(FAST_EXP2((SXP)[mi][1][0]), FAST_EXP2((SXP)[mi][1][1])); \
      pk_.u[3] = pack2bf(FAST_EXP2((SXP)[mi][1][2]), FAST_EXP2((SXP)[mi][1][3])); \
      (PB)[mi] = pk_.v;                                                    \
    }                                                                      \
  } while (0)

  // PV(slot SP, PB) interleaved with exp(SX) -> PBN
#define PHASE_C(SP, PB, SX, PBN) do {                                      \
    bf16x8 va0 = *(const bf16x8*)(vap0 + (SP) * 4096);                     \
    bf16x8 va1 = *(const bf16x8*)(vap1 + (SP) * 4096);                     \
    bf16x8 va2 = *(const bf16x8*)(vap2 + (SP) * 4096);                     \
    bf16x8 va3 = *(const bf16x8*)(vap3 + (SP) * 4096);                     \
    _Pragma("unroll")                                                      \
    for (int mi = 0; mi < 4; ++mi) {                                       \
      oT[mi][0] = __builtin_amdgcn_mfma_f32_16x16x32_bf16(va0, (PB)[mi], oT[mi][0], 0, 0, 0); \
      oT[mi][1] = __builtin_amdgcn_mfma_f32_16x16x32_bf16(va1, (PB)[mi], oT[mi][1], 0, 0, 0); \
      oT[mi][2] = __builtin_amdgcn_mfma_f32_16x16x32_bf16(va2, (PB)[mi], oT[mi][2], 0, 0, 0); \
      oT[mi][3] = __builtin_amdgcn_mfma_f32_16x16x32_bf16(va3, (PB)[mi], oT[mi][3], 0, 0, 0); \
      oL[mi]    = __builtin_amdgcn_mfma_f32_16x16x32_bf16(vone, (PB)[mi], oL[mi], 0, 0, 0); \
      union { bf16x8 v; uint32_t u[4]; } pk_;                              \
      pk_.u[0] = pack2bf(FAST_EXP2((SX)[mi][0][0]), FAST_EXP2((SX)[mi][0][1])); \
      pk_.u[1] = pack2bf(FAST_EXP2((SX)[mi][0][2]), FAST_EXP2((SX)[mi][0][3])); \
      pk_.u[2] = pack2bf(FAST_EXP2((SX)[mi][1][0]), FAST_EXP2((SX)[mi][1][1])); \
      pk_.u[3] = pack2bf(FAST_EXP2((SX)[mi][1][2]), FAST_EXP2((SX)[mi][1][3])); \
      (PBN)[mi] = pk_.v;                                                   \
    }                                                                      \
  } while (0)

  // bare PV (setprio-wrapped)
#define PHASE_B(SP, PB) do {                                               \
    __builtin_amdgcn_s_setprio(1);                                         \
    {                                                                      \
      bf16x8 va0 = *(const bf16x8*)(vap0 + (SP) * 4096);                   \
      bf16x8 va1 = *(const bf16x8*)(vap1 + (SP) * 4096);                   \
      bf16x8 va2 = *(const bf16x8*)(vap2 + (SP) * 4096);                   \
      bf16x8 va3 = *(const bf16x8*)(vap3 + (SP) * 4096);                   \
      _Pragma("unroll")                                                    \
      for (int mi = 0; mi < 4; ++mi) {                                     \
        oT[mi][0] = __builtin_amdgcn_mfma_f32_16x16x32_bf16(va0, (PB)[mi], oT[mi][0], 0, 0, 0); \
        oT[mi][1] = __builtin_amdgcn_mfma_f32_16x16x32_bf16(va1, (PB)[mi], oT[mi][1], 0, 0, 0); \
        oT[mi][2] = __builtin_amdgcn_mfma_f32_16x16x32_bf16(va2, (PB)[mi], oT[mi][2], 0, 0, 0); \
        oT[mi][3] = __builtin_amdgcn_mfma_f32_16x16x32_bf16(va3, (PB)[mi], oT[mi][3], 0, 0, 0); \
        oL[mi]    = __builtin_amdgcn_mfma_f32_16x16x32_bf16(vone, (PB)[mi], oL[mi], 0, 0, 0); \
      }                                                                    \
    }                                                                      \
    __builtin_amdgcn_s_setprio(0);                                         \
  } while (0)

  // prologue: stage tiles 0,1
  STAGE(0, 0);
  STAGE(1, 1);
  __syncthreads();                              // drains vmcnt -> visible
  for (int P = 0; P < 16; ++P) {
    int tb = 4 * P;
    // interval 1: tiles tb(s0), tb+1(s1); stage tb+2->s2, tb+3->s3
    STAGE(2, (tb + 2) & 63);
    STAGE(3, (tb + 3) & 63);
    QK4(0, sxA);
    PHASE_A(1, sxB, sxA, pbA);                  // QK(tb+1) || exp(tb)
    PHASE_C(0, pbA, sxB, pbB);                  // PV(tb)   || exp(tb+1)
    PHASE_B(1, pbB);                            // PV(tb+1)
    __syncthreads();
    // interval 2: tiles tb+2(s2), tb+3(s3); stage tb+4->s0, tb+5->s1
    STAGE(0, (tb + 4) & 63);                    // wrap: harmless re-stage
    STAGE(1, (tb + 5) & 63);
    QK4(2, sxA);
    PHASE_A(3, sxB, sxA, pbA);
    PHASE_C(2, pbA, sxB, pbB);
    PHASE_B(3, pbB);
    __syncthreads();
  }
#undef STAGE
#undef QK4
#undef PHASE_A
#undef PHASE_C
#undef PHASE_B

  // ---- combine key-split partials across wave pairs (ksel 0 <- 1) ----
  float ls[4];
#pragma unroll
  for (int mi = 0; mi < 4; ++mi) {
    float s = oL[mi][0];
    s += __shfl_xor(s, 16, 64);
    s += __shfl_xor(s, 32, 64);
    ls[mi] = s;
  }
  // per-qsel scratch: qsel0 -> Ks region (32 KB), qsel1 -> Vs region.
  // oT at lane stride 17 f32x4 (272 B); ls after (offset 64*68 floats).
  float* xb = (qsel == 0) ? (float*)&Ks[0][0] : (float*)&Vs[0][0];
  float* xl = xb + 64 * 68;
  // main loop ended with __syncthreads(): all tile reads complete.
  if (ksel == 1) {
    f32x4* dst = (f32x4*)xb + (size_t)lane * 17;
#pragma unroll
    for (int mi = 0; mi < 4; ++mi)
#pragma unroll
      for (int db = 0; db < 4; ++db) dst[mi * 4 + db] = oT[mi][db];
    float* dl = xl + lane * 4;
#pragma unroll
    for (int mi = 0; mi < 4; ++mi) dl[mi] = ls[mi];
  }
  __syncthreads();
  if (ksel == 0) {
    const f32x4* src = (const f32x4*)xb + (size_t)lane * 17;
    const float* sl = xl + lane * 4;
#pragma unroll
    for (int mi = 0; mi < 4; ++mi) {
      float inv = 1.0f / (ls[mi] + sl[mi]);
      int qrow = q0 + mi * 16 + l15;
#pragma unroll
      for (int db = 0; db < 4; ++db) {
        f32x4 o = oT[mi][db] + src[mi * 4 + db];
        union { bf16x4 v; uint32_t u[2]; } ov;
        ov.u[0] = pack2bf(o[0] * inv, o[1] * inv);
        ov.u[1] = pack2bf(o[2] * inv, o[3] * inv);
        *(bf16x4*)(AT + (size_t)qrow * DIMM + h * 64 + db * 16 + quad * 4) = ov.v;
      }
    }
  }
}

// ---------------- output GEMM: AT (4096x1024) @ Wout^T + bias -> f32 -------
__global__ __launch_bounds__(256) void gemm_out_kernel(
    const unsigned short* __restrict__ AT, const unsigned short* __restrict__ WOT,
    const float* __restrict__ ba, const float* __restrict__ bx,
    float* __restrict__ out) {
  __shared__ unsigned short As[4 * 2048], Bs[4 * 4096];   // 48 KB
  int n0 = blockIdx.x * 128, m0 = blockIdx.y * 64;
  int s = (m0 >= 2048) ? 1 : 0;                 // 0 = a-stream rows, 1 = x
  const unsigned short* Ag = AT + (size_t)m0 * 1024;
  const unsigned short* Bg = WOT + (size_t)s * 1024 * 1024 + (size_t)n0 * 1024;
  f32x4 acc[2][4];
  gemm64_mainloop(Ag, Bg, As, Bs, acc);
  int t = threadIdx.x, lane = t & 63, wid = t >> 6;
  int wm = (wid >> 1) * 32, wn = (wid & 1) * 64;
  int l15 = lane & 15, quad = lane >> 4;
  const float* bias = s ? bx : ba;
  // d_out = [out_x (2048x1024) | out_a (2048x1024)]
  float* obase = s ? (out + (size_t)(m0 - 2048) * 1024)
                   : (out + (size_t)2048 * 1024 + (size_t)m0 * 1024);
#pragma unroll
  for (int mi = 0; mi < 2; ++mi)
#pragma unroll
    for (int r = 0; r < 4; ++r) {
      int row = wm + mi * 16 + quad * 4 + r;
#pragma unroll
      for (int j = 0; j < 4; ++j) {
        int col = n0 + wn + j * 16 + l15;
        obase[(size_t)row * 1024 + col] = acc[mi][j][r] + bias[col];
      }
    }
}

// ---------------------------------------------------------------------------
extern "C" void kernel_launch(void* const* d_in, const int* in_sizes, int n_in,
                              void* d_out, int out_size, void* d_ws, size_t ws_size,
                              hipStream_t stream) {
  const float* x      = (const float*)d_in[0];
  const float* a      = (const float*)d_in[1];
  const float* g_x    = (const float*)d_in[2];
  const float* g_a    = (const float*)d_in[3];
  const float* Wq_x   = (const float*)d_in[4];
  const float* Wkv_x  = (const float*)d_in[5];
  const float* Wq_a   = (const float*)d_in[6];
  const float* Wkv_a  = (const float*)d_in[7];
  const float* Wout_x = (const float*)d_in[8];
  const float* bout_x = (const float*)d_in[9];
  const float* Wout_a = (const float*)d_in[10];
  const float* bout_a = (const float*)d_in[11];
  float* out = (float*)d_out;

  // workspace (30.5 MB). AT aliases XN (dead after gemm_qkv).
  char* ws = (char*)d_ws;
  const size_t MB = 1024 * 1024;
  unsigned short* XN   = (unsigned short*)(ws);            // 8 MB
  unsigned short* WQT  = (unsigned short*)(ws + 8 * MB);   // 4 MB
  unsigned short* WKVT = (unsigned short*)(ws + 12 * MB);  // 2 MB
  unsigned short* WOT  = (unsigned short*)(ws + 14 * MB);  // 4 MB
  unsigned short* QB   = (unsigned short*)(ws + 18 * MB);  // 8 MB
  unsigned short* KB   = (unsigned short*)(ws + 26 * MB);  // 2 MB
  unsigned short* VT   = (unsigned short*)(ws + 28 * MB);  // 2 MB
  float* cosT          = (float*)(ws + 30 * MB);           // 256 KB
  float* sinT          = (float*)(ws + 30 * MB + 262144);  // 256 KB
  unsigned short* AT   = XN;                               // alias

  prep_kernel<<<dim3(10496), dim3(256), 0, stream>>>(
      a, x, g_a, g_x, Wq_a, Wq_x, Wkv_a, Wkv_x, Wout_a, Wout_x,
      XN, WQT, WKVT, WOT, cosT, sinT);
  gemm_qkv_kernel<<<dim3(12, 64), dim3(256), 0, stream>>>(
      XN, WQT, WKVT, cosT, sinT, QB, KB, VT);
  attn_kernel<<<dim3(32, 16), dim3(256), 0, stream>>>(QB, KB, VT, AT);
  gemm_out_kernel<<<dim3(8, 64), dim3(256), 0, stream>>>(
      AT, WOT, bout_a, bout_x, out);
}